// Round 9
// baseline (2143.384 us; speedup 1.0000x reference)
//
#include <hip/hip_runtime.h>

#define B_ 16
#define S_ 4096
#define D_ 256
#define H_ 256

typedef _Float16 h2 __attribute__((ext_vector_type(2)));
typedef _Float16 h8 __attribute__((ext_vector_type(8)));
typedef float f4 __attribute__((ext_vector_type(4)));

static __device__ __forceinline__ float fdot2f(h2 a, h2 b, float c) {
    return __builtin_amdgcn_fdot2(a, b, c, false);
}

// pure-VALU cross-lane via DPP; ctrl must be ICE
template <int CTRL>
static __device__ __forceinline__ float dpp_mv(float v) {
    int r = __builtin_amdgcn_update_dpp(0, __float_as_int(v), CTRL, 0xF, 0xF, true);
    return __int_as_float(r);
}
#define DPP_XOR1 0xB1    // quad_perm [1,0,3,2]  -> lane ^ 1
#define DPP_XOR2 0x4E    // quad_perm [2,3,0,1]  -> lane ^ 2
#define DPP_ROR4 0x124   // row_ror:4  (16-lane row rotation)
#define DPP_ROR8 0x128   // row_ror:8

// LDS-only barrier: drain LDS ops, NOT vmcnt (T4).
static __device__ __forceinline__ void lds_barrier() {
    asm volatile("s_waitcnt lgkmcnt(0)" ::: "memory");
    __builtin_amdgcn_s_barrier();
}

// h layout: 16B chunk c stored at chunk-slot c ^ (c>>3). The 16 slices'
// read #1 (chunks 0,2,..,30) and #2 (1,3,..,31) then hit each bank-quad
// exactly 2x per wave -> free (2-way aliasing).
static __device__ __forceinline__ int hswz(int i) {
    const int c = i >> 3, e = i & 7;
    return 8 * (c ^ (c >> 3)) + e;
}

// Kernel 1: xp[row][h] = sum_d x[row][d] * Wx[d][h] + bias[h], into d_out.
__global__ __launch_bounds__(256) void xproj_kernel(
    const float* __restrict__ x, const float* __restrict__ Wx,
    const float* __restrict__ bias, float* __restrict__ out)
{
    __shared__ float xs[32 * 256];
    const int tid = threadIdx.x;
    const long long row0 = (long long)blockIdx.x * 32;

    {
        const f4* __restrict__ xg = (const f4*)(x + row0 * D_);
        f4* xsv = (f4*)xs;
        #pragma unroll
        for (int k = 0; k < 8; ++k)
            xsv[tid + k * 256] = xg[tid + k * 256];
    }
    __syncthreads();

    const int j = tid;
    float acc[32];
    const float bj = bias[j];
    #pragma unroll
    for (int r = 0; r < 32; ++r) acc[r] = bj;

    for (int d4 = 0; d4 < D_ / 4; ++d4) {
        const float w0 = Wx[(d4 * 4 + 0) * H_ + j];
        const float w1 = Wx[(d4 * 4 + 1) * H_ + j];
        const float w2 = Wx[(d4 * 4 + 2) * H_ + j];
        const float w3 = Wx[(d4 * 4 + 3) * H_ + j];
        #pragma unroll
        for (int r = 0; r < 32; ++r) {
            f4 xv = *(const f4*)&xs[r * 256 + d4 * 4];
            acc[r] = fmaf(xv.x, w0, acc[r]);
            acc[r] = fmaf(xv.y, w1, acc[r]);
            acc[r] = fmaf(xv.z, w2, acc[r]);
            acc[r] = fmaf(xv.w, w3, acc[r]);
        }
    }
    #pragma unroll
    for (int r = 0; r < 32; ++r)
        out[(row0 + r) * H_ + j] = acc[r];
}

// Kernel 2: sequential scan, one block (CU) per batch, 512 threads
// (8 waves = 2/SIMD). Split-K x16: thread t -> slice sl=t&15 (16 i's,
// TWO b128 reads => only 16 LDS read instrs/CU/step), outputs
// j in [8g, 8g+8), g=t>>4 (w = 64 h2 regs, resident).
// 16-way reduce: DPP xor1+xor2 (reduce-scatter to 2 accs) then
// ror4+ror8 row all-reduce. Lane sl<8 owns j = 8g+sl: xp ring, tanh,
// store, publish. Per-step barrier is lgkmcnt-only.
__global__ __launch_bounds__(512, 2) void scan_kernel(
    const float* __restrict__ Wh, const float* __restrict__ state0,
    float* __restrict__ out)
{
    __shared__ __align__(16) _Float16 hbuf[2][H_];
    const int t = threadIdx.x;
    const int sl = t & 15;          // i-slice: i in [16sl, 16sl+16)
    const int g  = t >> 4;          // j-group: j in [8g, 8g+8)
    const int b = blockIdx.x;
    const bool b1 = (sl & 1) != 0;
    const bool b2 = (sl & 2) != 0;
    const bool owner = (sl < 8);
    const int j_own = 8 * g + sl;   // valid for owners

    // W[i][j] for i in [16sl,16sl+16), j in [8g,8g+8): 64 h2 regs
    h2 w[8][8];
    #pragma unroll
    for (int jj = 0; jj < 8; ++jj) {
        const int j = 8 * g + jj;
        #pragma unroll
        for (int p = 0; p < 8; ++p) {
            const int i = 16 * sl + 2 * p;
            h2 q;
            q[0] = (_Float16)Wh[(long long)i * H_ + j];
            q[1] = (_Float16)Wh[(long long)(i + 1) * H_ + j];
            w[jj][p] = q;
        }
    }

    if (t < H_) hbuf[0][hswz(t)] = (_Float16)state0[b * H_ + t];

    float* __restrict__ outb = out + (long long)b * S_ * H_;

    // xp prefetch ring, distance 4 (owner lanes only)
    float xr[4] = {0.f, 0.f, 0.f, 0.f};
    if (owner) {
        #pragma unroll
        for (int k = 0; k < 4; ++k)
            xr[k] = outb[(long long)k * H_ + j_own];
    }

    // slice read positions (f16 index), bank-spread by hswz
    const int o0 = hswz(16 * sl);
    const int o1 = hswz(16 * sl + 8);
    __syncthreads();

    #pragma unroll 4
    for (int st = 0; st < S_; ++st) {
        const int p = st & 1;
        const _Float16* hb = hbuf[p];

        union { h8 v; h2 q[4]; } u0, u1;
        u0.v = *(const h8*)&hb[o0];
        u1.v = *(const h8*)&hb[o1];

        float a[8];
        #pragma unroll
        for (int jj = 0; jj < 8; ++jj) {
            float ac = 0.f;
            ac = fdot2f(u0.q[0], w[jj][0], ac);
            ac = fdot2f(u0.q[1], w[jj][1], ac);
            ac = fdot2f(u0.q[2], w[jj][2], ac);
            ac = fdot2f(u0.q[3], w[jj][3], ac);
            ac = fdot2f(u1.q[0], w[jj][4], ac);
            ac = fdot2f(u1.q[1], w[jj][5], ac);
            ac = fdot2f(u1.q[2], w[jj][6], ac);
            ac = fdot2f(u1.q[3], w[jj][7], ac);
            a[jj] = ac;
        }

        // stage 1 (lane^1): keep jj with (jj&1)==(sl&1) -> 4 accs
        float k0 = b1 ? a[1] : a[0], s0 = b1 ? a[0] : a[1];
        float k1 = b1 ? a[3] : a[2], s1 = b1 ? a[2] : a[3];
        float k2 = b1 ? a[5] : a[4], s2 = b1 ? a[4] : a[5];
        float k3 = b1 ? a[7] : a[6], s3 = b1 ? a[6] : a[7];
        k0 += dpp_mv<DPP_XOR1>(s0);
        k1 += dpp_mv<DPP_XOR1>(s1);
        k2 += dpp_mv<DPP_XOR1>(s2);
        k3 += dpp_mv<DPP_XOR1>(s3);
        // stage 2 (lane^2): keep jj with (jj&2)==(sl&2) -> 2 accs
        float g0 = b2 ? k1 : k0, t0 = b2 ? k0 : k1;
        float g1 = b2 ? k3 : k2, t1 = b2 ? k2 : k3;
        g0 += dpp_mv<DPP_XOR2>(t0);   // jj = 0 + (sl&3)
        g1 += dpp_mv<DPP_XOR2>(t1);   // jj = 4 + (sl&3)
        // stages 3-4: row rotation all-reduce over the 4 quads of the 16-group
        g0 += dpp_mv<DPP_ROR4>(g0);
        g0 += dpp_mv<DPP_ROR8>(g0);
        g1 += dpp_mv<DPP_ROR4>(g1);
        g1 += dpp_mv<DPP_ROR8>(g1);
        // lane sl<4: g0 = full dot for j=8g+sl; lane 4<=sl<8: g1 = j=8g+sl

        if (owner) {
            const float v = (sl & 4) ? g1 : g0;
            const float pre = v + xr[st & 3];
            const float e = __builtin_amdgcn_exp2f(pre * 2.8853900817779268f);
            const float hn = fmaf(-2.f, __builtin_amdgcn_rcpf(e + 1.f), 1.f);

            outb[(long long)st * H_ + j_own] = hn;     // stays in flight
            hbuf[p ^ 1][hswz(j_own)] = (_Float16)hn;   // publish h for t+1

            const int nt = st + 4;
            xr[st & 3] = (nt < S_) ? outb[(long long)nt * H_ + j_own] : 0.f;
        }
        lds_barrier();   // lgkmcnt(0) + s_barrier - no vmcnt drain
    }
}

extern "C" void kernel_launch(void* const* d_in, const int* in_sizes, int n_in,
                              void* d_out, int out_size, void* d_ws, size_t ws_size,
                              hipStream_t stream) {
    const float* x  = (const float*)d_in[0];   // [B,S,D]
    const float* s0 = (const float*)d_in[1];   // [B,H]
    const float* Wx = (const float*)d_in[2];   // [D,H]
    const float* Wh = (const float*)d_in[3];   // [H,H]
    const float* bv = (const float*)d_in[4];   // [H]
    float* out = (float*)d_out;                // [B,S,H]

    xproj_kernel<<<dim3((B_ * S_) / 32), dim3(256), 0, stream>>>(x, Wx, bv, out);
    scan_kernel<<<dim3(B_), dim3(512), 0, stream>>>(Wh, s0, out);
}

// Round 10
// 1933.566 us; speedup vs baseline: 1.1085x; 1.1085x over previous
//
#include <hip/hip_runtime.h>

#define B_ 16
#define S_ 4096
#define D_ 256
#define H_ 256

typedef _Float16 h2 __attribute__((ext_vector_type(2)));
typedef _Float16 h8 __attribute__((ext_vector_type(8)));
typedef float f4 __attribute__((ext_vector_type(4)));

static __device__ __forceinline__ float fdot2f(h2 a, h2 b, float c) {
    return __builtin_amdgcn_fdot2(a, b, c, false);
}

template <int CTRL>
static __device__ __forceinline__ float dpp_mv(float v) {
    int r = __builtin_amdgcn_update_dpp(0, __float_as_int(v), CTRL, 0xF, 0xF, true);
    return __int_as_float(r);
}
#define DPP_XOR1 0xB1    // quad_perm [1,0,3,2] -> lane ^ 1
#define DPP_XOR2 0x4E    // quad_perm [2,3,0,1] -> lane ^ 2
#define DPP_ROR8 0x128   // row_ror:8 -> lane ^ 8 within 16-lane row

// LDS-only barrier: drain LDS ops, NOT vmcnt (T4).
static __device__ __forceinline__ void lds_barrier() {
    asm volatile("s_waitcnt lgkmcnt(0)" ::: "memory");
    __builtin_amdgcn_s_barrier();
}

// h storage: 16B chunk c (c = i>>3, 32 chunks) lives at slot
// rho(c) = (c>>2) | ((c&3)<<3).  Thread with slice sl reads chunks
// {4sl+k, k=0..3}: rho(4sl+k) = sl | (k<<3), so read instr k's 8 distinct
// chunks (sl=0..7) sit at slots {sl | 8k} -> slot&7 all distinct -> each
// instr covers all 32 banks exactly once: conflict-free, 128B/instr.
static __device__ __forceinline__ int hpos(int i) {
    const int c = i >> 3, e = i & 7;
    return 8 * ((c >> 2) | ((c & 3) << 3)) + e;
}

// Kernel 1: xp[row][h] = sum_d x[row][d] * Wx[d][h] + bias[h], into d_out.
__global__ __launch_bounds__(256) void xproj_kernel(
    const float* __restrict__ x, const float* __restrict__ Wx,
    const float* __restrict__ bias, float* __restrict__ out)
{
    __shared__ float xs[32 * 256];
    const int tid = threadIdx.x;
    const long long row0 = (long long)blockIdx.x * 32;

    {
        const f4* __restrict__ xg = (const f4*)(x + row0 * D_);
        f4* xsv = (f4*)xs;
        #pragma unroll
        for (int k = 0; k < 8; ++k)
            xsv[tid + k * 256] = xg[tid + k * 256];
    }
    __syncthreads();

    const int j = tid;
    float acc[32];
    const float bj = bias[j];
    #pragma unroll
    for (int r = 0; r < 32; ++r) acc[r] = bj;

    for (int d4 = 0; d4 < D_ / 4; ++d4) {
        const float w0 = Wx[(d4 * 4 + 0) * H_ + j];
        const float w1 = Wx[(d4 * 4 + 1) * H_ + j];
        const float w2 = Wx[(d4 * 4 + 2) * H_ + j];
        const float w3 = Wx[(d4 * 4 + 3) * H_ + j];
        #pragma unroll
        for (int r = 0; r < 32; ++r) {
            f4 xv = *(const f4*)&xs[r * 256 + d4 * 4];
            acc[r] = fmaf(xv.x, w0, acc[r]);
            acc[r] = fmaf(xv.y, w1, acc[r]);
            acc[r] = fmaf(xv.z, w2, acc[r]);
            acc[r] = fmaf(xv.w, w3, acc[r]);
        }
    }
    #pragma unroll
    for (int r = 0; r < 32; ++r)
        out[(row0 + r) * H_ + j] = acc[r];
}

// Kernel 2: scan, one block (CU) per batch, 256 threads (1 wave/SIMD).
// Thread t: slice sl = bits{0,1,3} of t (8 slices x 32 i's, 4 conflict-free
// b128 reads), outputs j in [8g,8g+8), g = bits{2,4..7}. 8-way reduce =
// DPP xor1 + xor2 + ror8 with keep/send selection; after it thread t holds
// the full dot for j_own = t with bits 2<->3 swapped (bijective). Every
// thread: xp ring load, tanh, store, h publish. lgkm-only barrier.
__global__ __launch_bounds__(256, 1) void scan_kernel(
    const float* __restrict__ Wh, const float* __restrict__ state0,
    float* __restrict__ out)
{
    __shared__ __align__(16) _Float16 hbuf[2][H_];
    const int t  = threadIdx.x;
    const int sl = (t & 3) | ((t >> 1) & 4);           // bits 0,1,3
    const int g  = ((t >> 2) & 1) | ((t >> 4) << 1);   // bits 2,4..7
    const int b  = blockIdx.x;
    const int j_own = 8 * g + sl;
    const bool s1 = (sl & 1) != 0, s2 = (sl & 2) != 0, s4 = (sl & 4) != 0;

    // W[i][j] for i in [32sl, 32sl+32), j in [8g, 8g+8): 128 h2 regs
    h2 w[8][16];
    #pragma unroll
    for (int jj = 0; jj < 8; ++jj) {
        const int j = 8 * g + jj;
        #pragma unroll
        for (int km = 0; km < 16; ++km) {
            const int i = 32 * sl + 8 * (km >> 2) + 2 * (km & 3);
            h2 q;
            q[0] = (_Float16)Wh[(long long)i * H_ + j];
            q[1] = (_Float16)Wh[(long long)(i + 1) * H_ + j];
            w[jj][km] = q;
        }
    }

    hbuf[0][hpos(t)] = (_Float16)state0[b * H_ + t];

    float* __restrict__ outb = out + (long long)b * S_ * H_;

    // xp prefetch ring, distance 4
    float xr[4];
    #pragma unroll
    for (int k = 0; k < 4; ++k)
        xr[k] = outb[(long long)k * H_ + j_own];

    // publish position for j_own (j_own>>3 == g, j_own&7 == sl)
    const int ppos = 8 * ((g >> 2) | ((g & 3) << 3)) + sl;
    const int rbase = 8 * sl;   // read base: chunk 4sl+k at f16-pos 8sl+64k
    __syncthreads();

    #pragma unroll 4
    for (int st = 0; st < S_; ++st) {
        const int p = st & 1;
        const _Float16* hb = hbuf[p];

        union { h8 v; h2 q[4]; } u0, u1, u2, u3;
        u0.v = *(const h8*)&hb[rbase];
        u1.v = *(const h8*)&hb[rbase + 64];
        u2.v = *(const h8*)&hb[rbase + 128];
        u3.v = *(const h8*)&hb[rbase + 192];

        float a[8];
        #pragma unroll
        for (int jj = 0; jj < 8; ++jj) a[jj] = 0.f;
        #pragma unroll
        for (int m = 0; m < 4; ++m) {
            #pragma unroll
            for (int jj = 0; jj < 8; ++jj) a[jj] = fdot2f(u0.q[m], w[jj][m], a[jj]);
        }
        #pragma unroll
        for (int m = 0; m < 4; ++m) {
            #pragma unroll
            for (int jj = 0; jj < 8; ++jj) a[jj] = fdot2f(u1.q[m], w[jj][4 + m], a[jj]);
        }
        #pragma unroll
        for (int m = 0; m < 4; ++m) {
            #pragma unroll
            for (int jj = 0; jj < 8; ++jj) a[jj] = fdot2f(u2.q[m], w[jj][8 + m], a[jj]);
        }
        #pragma unroll
        for (int m = 0; m < 4; ++m) {
            #pragma unroll
            for (int jj = 0; jj < 8; ++jj) a[jj] = fdot2f(u3.q[m], w[jj][12 + m], a[jj]);
        }

        // 8-way reduce-scatter (DPP): stage1 lane^1 — keep jj&1 == sl&1
        float k0 = s1 ? a[1] : a[0], d0 = s1 ? a[0] : a[1];
        float k1 = s1 ? a[3] : a[2], d1 = s1 ? a[2] : a[3];
        float k2 = s1 ? a[5] : a[4], d2 = s1 ? a[4] : a[5];
        float k3 = s1 ? a[7] : a[6], d3 = s1 ? a[6] : a[7];
        k0 += dpp_mv<DPP_XOR1>(d0);
        k1 += dpp_mv<DPP_XOR1>(d1);
        k2 += dpp_mv<DPP_XOR1>(d2);
        k3 += dpp_mv<DPP_XOR1>(d3);
        // stage2 lane^2 — keep jj&2 == sl&2
        float n0 = s2 ? k1 : k0, e0 = s2 ? k0 : k1;   // jj = (sl&3)
        float n1 = s2 ? k3 : k2, e1 = s2 ? k2 : k3;   // jj = 4 + (sl&3)
        n0 += dpp_mv<DPP_XOR2>(e0);
        n1 += dpp_mv<DPP_XOR2>(e1);
        // stage3 lane^8 (row_ror:8) — keep jj&4 == sl&4
        float v  = s4 ? n1 : n0, e2 = s4 ? n0 : n1;
        v += dpp_mv<DPP_ROR8>(e2);
        // v = full dot for j_own

        const float pre = v + xr[st & 3];
        const float e = __builtin_amdgcn_exp2f(pre * 2.8853900817779268f);
        const float hn = fmaf(-2.f, __builtin_amdgcn_rcpf(e + 1.f), 1.f);

        outb[(long long)st * H_ + j_own] = hn;   // stays in flight
        hbuf[p ^ 1][ppos] = (_Float16)hn;        // publish h for t+1

        const int nt = st + 4;
        xr[st & 3] = (nt < S_) ? outb[(long long)nt * H_ + j_own] : 0.f;
        lds_barrier();
    }
}

extern "C" void kernel_launch(void* const* d_in, const int* in_sizes, int n_in,
                              void* d_out, int out_size, void* d_ws, size_t ws_size,
                              hipStream_t stream) {
    const float* x  = (const float*)d_in[0];   // [B,S,D]
    const float* s0 = (const float*)d_in[1];   // [B,H]
    const float* Wx = (const float*)d_in[2];   // [D,H]
    const float* Wh = (const float*)d_in[3];   // [H,H]
    const float* bv = (const float*)d_in[4];   // [H]
    float* out = (float*)d_out;                // [B,S,H]

    xproj_kernel<<<dim3((B_ * S_) / 32), dim3(256), 0, stream>>>(x, Wx, bv, out);
    scan_kernel<<<dim3(B_), dim3(256), 0, stream>>>(Wh, s0, out);
}

// Round 11
// 1919.134 us; speedup vs baseline: 1.1168x; 1.0075x over previous
//
#include <hip/hip_runtime.h>

#define B_ 16
#define S_ 4096
#define D_ 256
#define H_ 256

typedef _Float16 h8v __attribute__((ext_vector_type(8)));
typedef float f4 __attribute__((ext_vector_type(4)));

// LDS-only barrier: drain LDS ops, NOT vmcnt (T4) — global store/load of the
// out buffer never aliases within the scan window.
static __device__ __forceinline__ void lds_barrier() {
    asm volatile("s_waitcnt lgkmcnt(0)" ::: "memory");
    __builtin_amdgcn_s_barrier();
}

// Kernel 1: xp[row][h] = sum_d x[row][d] * Wx[d][h] + bias[h], into d_out.
__global__ __launch_bounds__(256) void xproj_kernel(
    const float* __restrict__ x, const float* __restrict__ Wx,
    const float* __restrict__ bias, float* __restrict__ out)
{
    __shared__ float xs[32 * 256];
    const int tid = threadIdx.x;
    const long long row0 = (long long)blockIdx.x * 32;

    {
        const f4* __restrict__ xg = (const f4*)(x + row0 * D_);
        f4* xsv = (f4*)xs;
        #pragma unroll
        for (int k = 0; k < 8; ++k)
            xsv[tid + k * 256] = xg[tid + k * 256];
    }
    __syncthreads();

    const int j = tid;
    float acc[32];
    const float bj = bias[j];
    #pragma unroll
    for (int r = 0; r < 32; ++r) acc[r] = bj;

    for (int d4 = 0; d4 < D_ / 4; ++d4) {
        const float w0 = Wx[(d4 * 4 + 0) * H_ + j];
        const float w1 = Wx[(d4 * 4 + 1) * H_ + j];
        const float w2 = Wx[(d4 * 4 + 2) * H_ + j];
        const float w3 = Wx[(d4 * 4 + 3) * H_ + j];
        #pragma unroll
        for (int r = 0; r < 32; ++r) {
            f4 xv = *(const f4*)&xs[r * 256 + d4 * 4];
            acc[r] = fmaf(xv.x, w0, acc[r]);
            acc[r] = fmaf(xv.y, w1, acc[r]);
            acc[r] = fmaf(xv.z, w2, acc[r]);
            acc[r] = fmaf(xv.w, w3, acc[r]);
        }
    }
    #pragma unroll
    for (int r = 0; r < 32; ++r)
        out[(row0 + r) * H_ + j] = acc[r];
}

// Kernel 2: scan via MFMA with replicated rows. One block (CU) per batch,
// 256 threads = 4 waves. Wave w owns j in [64w, 64w+64) as 4 N-tiles.
// A-frag (M rows) = h replicated: lane reads h[32ks + 8kg .. +8] (16B
// broadcast across the 16 lanes of each kg group) -> every C row equal ->
// lane (kg,lc) of wave w holds the finished dot for j_own = 64w+16kg+lc
// in acc[kg][0]. No C exchange. VALU does epilogue only (~25 instrs).
__global__ __launch_bounds__(256, 1) void scan_kernel(
    const float* __restrict__ Wh, const float* __restrict__ state0,
    float* __restrict__ out)
{
    __shared__ __align__(16) _Float16 h_lds[2][H_];
    const int tid = threadIdx.x;
    const int l   = tid & 63;
    const int wav = tid >> 6;        // 0..3
    const int lc  = l & 15;
    const int kg  = l >> 4;          // 0..3
    const int b   = blockIdx.x;
    const int j_own = 64 * wav + 16 * kg + lc;   // bijection over 256 threads

    // B-frags: bf[nt][ks], lane holds Wh[k][j], j = 64wav+16nt+lc,
    // k = 32ks + 8kg + e  (same (kg,e)->k map as the A-frag: permutation-safe,
    // convention numerically verified in round 7).
    h8v bf[4][8];
    #pragma unroll
    for (int nt = 0; nt < 4; ++nt) {
        const int j = 64 * wav + 16 * nt + lc;
        #pragma unroll
        for (int ks = 0; ks < 8; ++ks) {
            #pragma unroll
            for (int e = 0; e < 8; ++e) {
                const int k = 32 * ks + 8 * kg + e;
                bf[nt][ks][e] = (_Float16)Wh[k * H_ + j];
            }
        }
    }

    h_lds[0][tid] = (_Float16)state0[b * H_ + tid];

    float* __restrict__ outb = out + (long long)b * S_ * H_;

    // xp prefetch ring, distance 4 (static indices via unroll-4)
    float xr[4];
    #pragma unroll
    for (int k = 0; k < 4; ++k)
        xr[k] = outb[(long long)k * H_ + j_own];
    __syncthreads();

    const int abase = 8 * kg;   // f16 offset of this lane's A slice within a ks

    #pragma unroll 4
    for (int st = 0; st < S_; ++st) {
        const int p = st & 1;
        const _Float16* hb = h_lds[p];

        // 8 broadcast A-frags (16B each; 4 distinct addrs per wave)
        h8v af[8];
        #pragma unroll
        for (int ks = 0; ks < 8; ++ks)
            af[ks] = *(const h8v*)&hb[32 * ks + abase];

        f4 acc0 = {0.f, 0.f, 0.f, 0.f};
        f4 acc1 = {0.f, 0.f, 0.f, 0.f};
        f4 acc2 = {0.f, 0.f, 0.f, 0.f};
        f4 acc3 = {0.f, 0.f, 0.f, 0.f};
        #pragma unroll
        for (int ks = 0; ks < 8; ++ks) {
            acc0 = __builtin_amdgcn_mfma_f32_16x16x32_f16(af[ks], bf[0][ks], acc0, 0, 0, 0);
            acc1 = __builtin_amdgcn_mfma_f32_16x16x32_f16(af[ks], bf[1][ks], acc1, 0, 0, 0);
            acc2 = __builtin_amdgcn_mfma_f32_16x16x32_f16(af[ks], bf[2][ks], acc2, 0, 0, 0);
            acc3 = __builtin_amdgcn_mfma_f32_16x16x32_f16(af[ks], bf[3][ks], acc3, 0, 0, 0);
        }

        // all C rows equal (replicated A): lane's value for j_own is in
        // acc[kg][any reg]; select nt == kg (3 cndmask).
        float v = acc0[0];
        v = (kg == 1) ? acc1[0] : v;
        v = (kg == 2) ? acc2[0] : v;
        v = (kg == 3) ? acc3[0] : v;

        const float pre = v + xr[st & 3];
        const float e = __builtin_amdgcn_exp2f(pre * 2.8853900817779268f);
        const float hn = fmaf(-2.f, __builtin_amdgcn_rcpf(e + 1.f), 1.f);

        outb[(long long)st * H_ + j_own] = hn;    // stays in flight (no vmcnt drain)
        h_lds[p ^ 1][j_own] = (_Float16)hn;       // publish h for t+1 (2-way banks: free)

        const int nt4 = st + 4;
        xr[st & 3] = (nt4 < S_) ? outb[(long long)nt4 * H_ + j_own] : 0.f;
        lds_barrier();
    }
}

extern "C" void kernel_launch(void* const* d_in, const int* in_sizes, int n_in,
                              void* d_out, int out_size, void* d_ws, size_t ws_size,
                              hipStream_t stream) {
    const float* x  = (const float*)d_in[0];   // [B,S,D]
    const float* s0 = (const float*)d_in[1];   // [B,H]
    const float* Wx = (const float*)d_in[2];   // [D,H]
    const float* Wh = (const float*)d_in[3];   // [H,H]
    const float* bv = (const float*)d_in[4];   // [H]
    float* out = (float*)d_out;                // [B,S,H]

    xproj_kernel<<<dim3((B_ * S_) / 32), dim3(256), 0, stream>>>(x, Wx, bv, out);
    scan_kernel<<<dim3(B_), dim3(256), 0, stream>>>(Wh, s0, out);
}